// Round 1
// baseline (702.082 us; speedup 1.0000x reference)
//
#include <hip/hip_runtime.h>
#include <hip/hip_bf16.h>

// Problem constants
#define BDIM 8
#define HDIM 64
#define WDIM 64
#define CDIM 192
#define CIDIM 384
#define MTOK (BDIM * HDIM * WDIM)   // 32768 tokens

using bf16 = __hip_bfloat16;

__device__ __forceinline__ float silu_f(float v) { return v / (1.0f + __expf(-v)); }
__device__ __forceinline__ float to_float(float v) { return v; }
__device__ __forceinline__ float to_float(bf16 v) { return __bfloat162float(v); }

// ---------------------------------------------------------------------------
// Tiled GEMM: C[M,N] = A[M,K] @ B[K,N] (+ epilogue)
// BM=BN=64, BK=16, 256 threads, 4x4 micro-tile per thread, fp32 accumulate.
// EPI: 0 = store bf16 plain            (xz = x@Win)
//      1 = +resid, store fp32          (out = x + y@Wout)
//      2 = silu(+bias), store bf16     (h = silu(out@Wm1+bm1))
//      3 = +bias +resid, store fp32    (final = out + h@Wm2 + bm2)
// ---------------------------------------------------------------------------
template <typename TA, int EPI>
__launch_bounds__(256)
__global__ void gemm_tiled(const TA* __restrict__ A, const float* __restrict__ Bw,
                           const float* __restrict__ bias, const float* __restrict__ resid,
                           float* __restrict__ outF, bf16* __restrict__ outB,
                           int M, int N, int K)
{
    __shared__ float As[16][64];   // [k][m]
    __shared__ float Bs[16][64];   // [k][n]

    const int tid  = threadIdx.x;
    const int m0   = blockIdx.y * 64;
    const int n0   = blockIdx.x * 64;
    const int trow = (tid >> 4) << 2;   // 0,4,...,60
    const int tcol = (tid & 15) << 2;

    float acc[4][4] = {};

    for (int k0 = 0; k0 < K; k0 += 16) {
        // A tile 64x16 -> As[k][m]; consecutive tids read consecutive k (coalesced 64B)
        #pragma unroll
        for (int i = 0; i < 4; ++i) {
            int idx = tid + i * 256;
            int r = idx >> 4, c = idx & 15;
            As[c][r] = to_float(A[(size_t)(m0 + r) * K + (k0 + c)]);
        }
        // B tile 16x64 -> Bs[k][n]; one float4 per thread (coalesced)
        {
            int r = tid >> 4;
            int c = (tid & 15) << 2;
            float4 v = *reinterpret_cast<const float4*>(&Bw[(size_t)(k0 + r) * N + (n0 + c)]);
            *reinterpret_cast<float4*>(&Bs[r][c]) = v;
        }
        __syncthreads();

        #pragma unroll
        for (int kk = 0; kk < 16; ++kk) {
            float4 a4 = *reinterpret_cast<const float4*>(&As[kk][trow]);
            float4 b4 = *reinterpret_cast<const float4*>(&Bs[kk][tcol]);
            float av[4] = {a4.x, a4.y, a4.z, a4.w};
            float bv[4] = {b4.x, b4.y, b4.z, b4.w};
            #pragma unroll
            for (int i = 0; i < 4; ++i)
                #pragma unroll
                for (int j = 0; j < 4; ++j)
                    acc[i][j] += av[i] * bv[j];
        }
        __syncthreads();
    }

    #pragma unroll
    for (int i = 0; i < 4; ++i) {
        const size_t m = (size_t)(m0 + trow + i);
        #pragma unroll
        for (int j = 0; j < 4; ++j) {
            const int n = n0 + tcol + j;
            float v = acc[i][j];
            if constexpr (EPI == 0) {
                outB[m * N + n] = __float2bfloat16(v);
            } else if constexpr (EPI == 1) {
                outF[m * N + n] = v + resid[m * N + n];
            } else if constexpr (EPI == 2) {
                outB[m * N + n] = __float2bfloat16(silu_f(v + bias[n]));
            } else {
                outF[m * N + n] = v + bias[n] + resid[m * N + n];
            }
        }
    }
}

// ---------------------------------------------------------------------------
// Depthwise 3x3 conv (channels-last) + bias + silu, x4 scan-merge, gate by silu(z).
// xz layout: [M, 768] bf16; x1 = xz[:, 0:384], z = xz[:, 384:768].
// One block per pixel m, 384 threads = one channel each.
// y[m,ci] = 4 * silu(conv + b[ci]) * silu(z[m,ci])
// ---------------------------------------------------------------------------
__launch_bounds__(384)
__global__ void dwconv_gate(const bf16* __restrict__ xz, const float* __restrict__ conv_w,
                            const float* __restrict__ conv_b, bf16* __restrict__ y)
{
    const int m  = blockIdx.x;
    const int ci = threadIdx.x;            // 0..383
    const int b  = m >> 12;                // /4096
    const int pix = m & 4095;
    const int h  = pix >> 6;
    const int w  = pix & 63;

    float wreg[9];
    #pragma unroll
    for (int j = 0; j < 9; ++j) wreg[j] = conv_w[ci * 9 + j];

    float acc = conv_b[ci];
    #pragma unroll
    for (int dh = -1; dh <= 1; ++dh) {
        const int hh = h + dh;
        if (hh < 0 || hh >= HDIM) continue;
        #pragma unroll
        for (int dw = -1; dw <= 1; ++dw) {
            const int ww = w + dw;
            if (ww < 0 || ww >= WDIM) continue;
            const int mm = (b << 12) + (hh << 6) + ww;
            acc += __bfloat162float(xz[(size_t)mm * 768 + ci]) * wreg[(dh + 1) * 3 + (dw + 1)];
        }
    }
    const float zv = __bfloat162float(xz[(size_t)m * 768 + CIDIM + ci]);
    y[(size_t)m * CIDIM + ci] = __float2bfloat16(4.0f * silu_f(acc) * silu_f(zv));
}

// ---------------------------------------------------------------------------
extern "C" void kernel_launch(void* const* d_in, const int* in_sizes, int n_in,
                              void* d_out, int out_size, void* d_ws, size_t ws_size,
                              hipStream_t stream)
{
    const float* x      = (const float*)d_in[0];   // [M, 192]
    const float* Win    = (const float*)d_in[1];   // [192, 768]
    const float* conv_w = (const float*)d_in[2];   // [384, 1, 3, 3]
    const float* conv_b = (const float*)d_in[3];   // [384]
    const float* Wout   = (const float*)d_in[4];   // [384, 192]
    const float* Wm1    = (const float*)d_in[5];   // [192, 768]
    const float* bm1    = (const float*)d_in[6];   // [768]
    const float* Wm2    = (const float*)d_in[7];   // [768, 192]
    const float* bm2    = (const float*)d_in[8];   // [192]
    float* out = (float*)d_out;                    // [M, 192] fp32

    char* ws = (char*)d_ws;
    bf16* ws_xz = (bf16*)ws;                             // [M, 768] bf16 (50.3 MB)
    bf16* ws_y  = (bf16*)(ws + (size_t)MTOK * 768 * 2);  // [M, 384] bf16 (25.2 MB)
    bf16* ws_h  = ws_xz;                                 // reuse xz region for h [M,768]

    const dim3 blk(256);

    // 1) xz = x @ Win   [M,768], K=192  -> bf16 ws_xz
    gemm_tiled<float, 0><<<dim3(768 / 64, MTOK / 64), blk, 0, stream>>>(
        x, Win, nullptr, nullptr, nullptr, ws_xz, MTOK, 768, CDIM);

    // 2) y = 4*silu(dwconv(x1)+b) * silu(z)  -> bf16 ws_y
    dwconv_gate<<<dim3(MTOK), dim3(384), 0, stream>>>(ws_xz, conv_w, conv_b, ws_y);

    // 3) out = x + y @ Wout   [M,192], K=384 -> fp32 d_out
    gemm_tiled<bf16, 1><<<dim3(192 / 64, MTOK / 64), blk, 0, stream>>>(
        ws_y, Wout, nullptr, x, out, nullptr, MTOK, CDIM, CIDIM);

    // 4) h = silu(out @ Wm1 + bm1)   [M,768], K=192 -> bf16 ws_h
    gemm_tiled<float, 2><<<dim3(768 / 64, MTOK / 64), blk, 0, stream>>>(
        out, Wm1, bm1, nullptr, nullptr, ws_h, MTOK, 768, CDIM);

    // 5) final = out + h @ Wm2 + bm2   [M,192], K=768 -> fp32 d_out (in-place add)
    gemm_tiled<bf16, 3><<<dim3(192 / 64, MTOK / 64), blk, 0, stream>>>(
        ws_h, Wm2, bm2, out, out, nullptr, MTOK, CDIM, 768);
}

// Round 2
// 231.328 us; speedup vs baseline: 3.0350x; 3.0350x over previous
//
#include <hip/hip_runtime.h>
#include <hip/hip_bf16.h>

// Problem constants
#define BDIM 8
#define HDIM 64
#define WDIM 64
#define CDIM 192
#define CIDIM 384
#define MTOK (BDIM * HDIM * WDIM)   // 32768 tokens

using bf16 = __hip_bfloat16;
typedef __attribute__((ext_vector_type(8))) short short8;   // 8 bf16 (4 VGPRs)
typedef __attribute__((ext_vector_type(4))) float f32x4;

__device__ __forceinline__ float silu_f(float v) { return v / (1.0f + __expf(-v)); }

// async global->LDS, 16B per lane. LDS dest must be WAVE-UNIFORM base; HW adds lane*16.
__device__ __forceinline__ void gload_lds16(const bf16* g, bf16* l) {
    __builtin_amdgcn_global_load_lds(
        (const __attribute__((address_space(1))) void*)g,
        (__attribute__((address_space(3))) void*)l, 16, 0, 0);
}

// ---------------------------------------------------------------------------
// MFMA GEMM: C[M,N] = A[M,K] @ B[K,N], A bf16 [M,K], B given TRANSPOSED bf16 [N,K].
// BM=128, BN=64, BK=64. 256 threads = 4 waves in 2x2; wave tile 64x32 (4x2 frags).
// LDS linear [rows][64] bf16, 16B slots XOR-swizzled: physical slot s holds
// logical slot s^(row&7). Staging pre-swizzles the GLOBAL source address
// (global_load_lds dest is linear); fragment reads apply the same XOR.
// EPI: 0 = store bf16                      (xz = x@Win)
//      1 = +resid -> fp32 AND bf16         (out = x + y@Wout)
//      2 = silu(+bias) -> bf16             (h = silu(out@Wm1+bm1))
//      3 = +bias +resid -> fp32            (final = out + h@Wm2 + bm2)
// ---------------------------------------------------------------------------
template <int EPI>
__launch_bounds__(256, 4)
__global__ void gemm_mfma(const bf16* __restrict__ A, const bf16* __restrict__ BT,
                          const float* __restrict__ bias, const float* __restrict__ resid,
                          float* __restrict__ outF, bf16* __restrict__ outB,
                          int M, int N, int K)
{
    __shared__ bf16 As[128 * 64];
    __shared__ bf16 Bs[64 * 64];

    const int tid  = threadIdx.x;
    const int lane = tid & 63;
    const int wv   = tid >> 6;          // 0..3
    const int wm   = wv >> 1;           // 0..1 (row half)
    const int wn   = wv & 1;            // 0..1 (col half)
    const int m0   = blockIdx.y * 128;
    const int n0   = blockIdx.x * 64;

    const int srow  = lane >> 3;        // staging: 8 lanes per 128B row
    const int sslot = lane & 7;

    f32x4 acc[4][2] = {};

    for (int k0 = 0; k0 < K; k0 += 64) {
        // stage A rows [wv*32, wv*32+32): 4 instrs x 8 rows
        #pragma unroll
        for (int i = 0; i < 4; ++i) {
            const int rb = wv * 32 + i * 8;
            const int r  = rb + srow;
            gload_lds16(A + (size_t)(m0 + r) * K + k0 + ((sslot ^ (r & 7)) << 3),
                        &As[rb * 64]);
        }
        // stage B rows [wv*16, wv*16+16): 2 instrs x 8 rows
        #pragma unroll
        for (int i = 0; i < 2; ++i) {
            const int rb = wv * 16 + i * 8;
            const int r  = rb + srow;
            gload_lds16(BT + (size_t)(n0 + r) * K + k0 + ((sslot ^ (r & 7)) << 3),
                        &Bs[rb * 64]);
        }
        __syncthreads();   // compiler drains vmcnt before s_barrier

        #pragma unroll
        for (int kk = 0; kk < 2; ++kk) {
            const int t = kk * 4 + (lane >> 4);   // 16B slot index in row
            short8 af[4], bfr[2];
            #pragma unroll
            for (int mi = 0; mi < 4; ++mi) {
                const int m = wm * 64 + mi * 16 + (lane & 15);
                af[mi] = *reinterpret_cast<const short8*>(&As[m * 64 + ((t ^ (m & 7)) << 3)]);
            }
            #pragma unroll
            for (int ni = 0; ni < 2; ++ni) {
                const int n = wn * 32 + ni * 16 + (lane & 15);
                bfr[ni] = *reinterpret_cast<const short8*>(&Bs[n * 64 + ((t ^ (n & 7)) << 3)]);
            }
            #pragma unroll
            for (int mi = 0; mi < 4; ++mi)
                #pragma unroll
                for (int ni = 0; ni < 2; ++ni)
                    acc[mi][ni] = __builtin_amdgcn_mfma_f32_16x16x32_bf16(
                        af[mi], bfr[ni], acc[mi][ni], 0, 0, 0);
        }
        __syncthreads();
    }

    // epilogue: C/D layout col = lane&15, row = (lane>>4)*4 + j  [m89-verified]
    const int colb = n0 + wn * 32 + (lane & 15);
    const int rowb = m0 + wm * 64 + (lane >> 4) * 4;
    #pragma unroll
    for (int mi = 0; mi < 4; ++mi) {
        #pragma unroll
        for (int ni = 0; ni < 2; ++ni) {
            const int c = colb + ni * 16;
            #pragma unroll
            for (int j = 0; j < 4; ++j) {
                const int row = rowb + mi * 16 + j;
                const size_t off = (size_t)row * N + c;
                const float v = acc[mi][ni][j];
                if constexpr (EPI == 0) {
                    outB[off] = __float2bfloat16(v);
                } else if constexpr (EPI == 1) {
                    const float r = v + resid[off];
                    outF[off] = r;
                    outB[off] = __float2bfloat16(r);
                } else if constexpr (EPI == 2) {
                    outB[off] = __float2bfloat16(silu_f(v + bias[c]));
                } else {
                    outF[off] = v + bias[c] + resid[off];
                }
            }
        }
    }
}

// ---------------------------------------------------------------------------
// Depthwise 3x3 conv (channels-last) + bias + silu, x4 scan-merge, gate silu(z).
// xz: [M,768] bf16; x1 = [:,0:384], z = [:,384:768]. One block per pixel.
// ---------------------------------------------------------------------------
__launch_bounds__(384)
__global__ void dwconv_gate(const bf16* __restrict__ xz, const float* __restrict__ conv_w,
                            const float* __restrict__ conv_b, bf16* __restrict__ y)
{
    const int m  = blockIdx.x;
    const int ci = threadIdx.x;            // 0..383
    const int b  = m >> 12;
    const int pix = m & 4095;
    const int h  = pix >> 6;
    const int w  = pix & 63;

    float wreg[9];
    #pragma unroll
    for (int j = 0; j < 9; ++j) wreg[j] = conv_w[ci * 9 + j];

    float acc = conv_b[ci];
    #pragma unroll
    for (int dh = -1; dh <= 1; ++dh) {
        const int hh = h + dh;
        if (hh < 0 || hh >= HDIM) continue;
        #pragma unroll
        for (int dw = -1; dw <= 1; ++dw) {
            const int ww = w + dw;
            if (ww < 0 || ww >= WDIM) continue;
            const int mm = (b << 12) + (hh << 6) + ww;
            acc += __bfloat162float(xz[(size_t)mm * 768 + ci]) * wreg[(dh + 1) * 3 + (dw + 1)];
        }
    }
    const float zv = __bfloat162float(xz[(size_t)m * 768 + CIDIM + ci]);
    y[(size_t)m * CIDIM + ci] = __float2bfloat16(4.0f * silu_f(acc) * silu_f(zv));
}

// ---------------------------------------------------------------------------
// fp32 -> bf16 convert (x), 4 elems/thread
__launch_bounds__(256)
__global__ void cvt_to_bf16(const float* __restrict__ in, bf16* __restrict__ out, int n)
{
    const int i = (blockIdx.x * 256 + threadIdx.x) * 4;
    if (i < n) {
        const float4 v = *reinterpret_cast<const float4*>(&in[i]);
        out[i + 0] = __float2bfloat16(v.x);
        out[i + 1] = __float2bfloat16(v.y);
        out[i + 2] = __float2bfloat16(v.z);
        out[i + 3] = __float2bfloat16(v.w);
    }
}

// fp32 [R][C] -> bf16 [C][R] (weight transpose; tiny matrices)
__launch_bounds__(256)
__global__ void transpose_to_bf16(const float* __restrict__ in, bf16* __restrict__ out,
                                  int R, int C)
{
    const int idx = blockIdx.x * 256 + threadIdx.x;
    if (idx < R * C) {
        const int r = idx / C, c = idx % C;
        out[(size_t)c * R + r] = __float2bfloat16(in[idx]);
    }
}

// ---------------------------------------------------------------------------
extern "C" void kernel_launch(void* const* d_in, const int* in_sizes, int n_in,
                              void* d_out, int out_size, void* d_ws, size_t ws_size,
                              hipStream_t stream)
{
    const float* x      = (const float*)d_in[0];   // [M,192]
    const float* Win    = (const float*)d_in[1];   // [192,768]
    const float* conv_w = (const float*)d_in[2];   // [384,1,3,3]
    const float* conv_b = (const float*)d_in[3];   // [384]
    const float* Wout   = (const float*)d_in[4];   // [384,192]
    const float* Wm1    = (const float*)d_in[5];   // [192,768]
    const float* bm1    = (const float*)d_in[6];   // [768]
    const float* Wm2    = (const float*)d_in[7];   // [768,192]
    const float* bm2    = (const float*)d_in[8];   // [192]
    float* out = (float*)d_out;                    // [M,192] fp32

    char* ws = (char*)d_ws;
    size_t o = 0;
    bf16* xb    = (bf16*)(ws + o); o += (size_t)MTOK * CDIM * 2;      // 12.58 MB
    bf16* WinT  = (bf16*)(ws + o); o += (size_t)768 * 192 * 2;        // [768,192]
    bf16* WoutT = (bf16*)(ws + o); o += (size_t)192 * 384 * 2;        // [192,384]
    bf16* Wm1T  = (bf16*)(ws + o); o += (size_t)768 * 192 * 2;        // [768,192]
    bf16* Wm2T  = (bf16*)(ws + o); o += (size_t)192 * 768 * 2;        // [192,768]
    bf16* ws_xz = (bf16*)(ws + o); o += (size_t)MTOK * 768 * 2;       // 50.3 MB
    bf16* ws_y  = (bf16*)(ws + o); o += (size_t)MTOK * CIDIM * 2;     // 25.2 MB
    bf16* ws_ob = (bf16*)(ws + o); o += (size_t)MTOK * CDIM * 2;      // 12.58 MB
    bf16* ws_h  = ws_xz;   // reuse xz region for h [M,768]

    // --- convert inputs to bf16 (weights transposed to [N,K]) ---
    {
        const int n = MTOK * CDIM;
        cvt_to_bf16<<<dim3(n / 4 / 256), dim3(256), 0, stream>>>(x, xb, n);
        transpose_to_bf16<<<dim3((192 * 768 + 255) / 256), dim3(256), 0, stream>>>(Win,  WinT, 192, 768);
        transpose_to_bf16<<<dim3((384 * 192 + 255) / 256), dim3(256), 0, stream>>>(Wout, WoutT, 384, 192);
        transpose_to_bf16<<<dim3((192 * 768 + 255) / 256), dim3(256), 0, stream>>>(Wm1,  Wm1T, 192, 768);
        transpose_to_bf16<<<dim3((768 * 192 + 255) / 256), dim3(256), 0, stream>>>(Wm2,  Wm2T, 768, 192);
    }

    // 1) xz = x @ Win   [M,768], K=192 -> bf16
    gemm_mfma<0><<<dim3(768 / 64, MTOK / 128), dim3(256), 0, stream>>>(
        xb, WinT, nullptr, nullptr, nullptr, ws_xz, MTOK, 768, CDIM);

    // 2) y = 4*silu(dwconv(x1)+b) * silu(z) -> bf16
    dwconv_gate<<<dim3(MTOK), dim3(384), 0, stream>>>(ws_xz, conv_w, conv_b, ws_y);

    // 3) out = x + y @ Wout   [M,192], K=384 -> fp32 d_out + bf16 ws_ob
    gemm_mfma<1><<<dim3(192 / 64, MTOK / 128), dim3(256), 0, stream>>>(
        ws_y, WoutT, nullptr, x, out, ws_ob, MTOK, CDIM, CIDIM);

    // 4) h = silu(out @ Wm1 + bm1)   [M,768], K=192 -> bf16 (aliases xz)
    gemm_mfma<2><<<dim3(768 / 64, MTOK / 128), dim3(256), 0, stream>>>(
        ws_ob, Wm1T, bm1, nullptr, nullptr, ws_h, MTOK, 768, CDIM);

    // 5) final = out + h @ Wm2 + bm2   [M,192], K=768 -> fp32 d_out (in-place)
    gemm_mfma<3><<<dim3(192 / 64, MTOK / 128), dim3(256), 0, stream>>>(
        ws_h, Wm2T, bm2, out, out, nullptr, MTOK, CDIM, 768);
}

// Round 3
// 175.233 us; speedup vs baseline: 4.0066x; 1.3201x over previous
//
#include <hip/hip_runtime.h>
#include <hip/hip_bf16.h>

// Problem constants
#define BDIM 8
#define HDIM 64
#define WDIM 64
#define CDIM 192
#define CIDIM 384
#define MTOK (BDIM * HDIM * WDIM)   // 32768 tokens

using bf16 = __hip_bfloat16;
typedef __attribute__((ext_vector_type(8))) short short8;   // 8 bf16 (4 VGPRs)
typedef __attribute__((ext_vector_type(4))) float f32x4;

__device__ __forceinline__ float silu_f(float v) { return v / (1.0f + __expf(-v)); }
__device__ __forceinline__ float bf2f(short s) {
    union { unsigned u; float f; } x; x.u = ((unsigned)(unsigned short)s) << 16; return x.f;
}

// async global->LDS, 16B per lane. LDS dest must be WAVE-UNIFORM base; HW adds lane*16.
__device__ __forceinline__ void gload_lds16(const bf16* g, bf16* l) {
    __builtin_amdgcn_global_load_lds(
        (const __attribute__((address_space(1))) void*)g,
        (__attribute__((address_space(3))) void*)l, 16, 0, 0);
}

// ---------------------------------------------------------------------------
// MFMA GEMM: C[M,N] = A[M,K] @ B[K,N], A bf16 [M,K], B given TRANSPOSED bf16 [N,K].
// BM=128, BN=64, BK=64. 256 threads = 4 waves in 2x2; wave tile 64x32 (4x2 frags).
// LDS linear [rows][64] bf16, 16B slots XOR-swizzled (both-sides: pre-swizzled
// global source + swizzled ds_read).
// EPI: 0 = store bf16; 1 = +resid -> fp32 + bf16; 2 = silu(+bias) -> bf16;
//      3 = +bias +resid -> fp32
// ---------------------------------------------------------------------------
template <int EPI>
__launch_bounds__(256, 4)
__global__ void gemm_mfma(const bf16* __restrict__ A, const bf16* __restrict__ BT,
                          const float* __restrict__ bias, const float* __restrict__ resid,
                          float* __restrict__ outF, bf16* __restrict__ outB,
                          int M, int N, int K)
{
    __shared__ bf16 As[128 * 64];
    __shared__ bf16 Bs[64 * 64];

    const int tid  = threadIdx.x;
    const int lane = tid & 63;
    const int wv   = tid >> 6;
    const int wm   = wv >> 1;
    const int wn   = wv & 1;
    const int m0   = blockIdx.y * 128;
    const int n0   = blockIdx.x * 64;

    const int srow  = lane >> 3;
    const int sslot = lane & 7;

    f32x4 acc[4][2] = {};

    for (int k0 = 0; k0 < K; k0 += 64) {
        #pragma unroll
        for (int i = 0; i < 4; ++i) {
            const int rb = wv * 32 + i * 8;
            const int r  = rb + srow;
            gload_lds16(A + (size_t)(m0 + r) * K + k0 + ((sslot ^ (r & 7)) << 3),
                        &As[rb * 64]);
        }
        #pragma unroll
        for (int i = 0; i < 2; ++i) {
            const int rb = wv * 16 + i * 8;
            const int r  = rb + srow;
            gload_lds16(BT + (size_t)(n0 + r) * K + k0 + ((sslot ^ (r & 7)) << 3),
                        &Bs[rb * 64]);
        }
        __syncthreads();

        #pragma unroll
        for (int kk = 0; kk < 2; ++kk) {
            const int t = kk * 4 + (lane >> 4);
            short8 af[4], bfr[2];
            #pragma unroll
            for (int mi = 0; mi < 4; ++mi) {
                const int m = wm * 64 + mi * 16 + (lane & 15);
                af[mi] = *reinterpret_cast<const short8*>(&As[m * 64 + ((t ^ (m & 7)) << 3)]);
            }
            #pragma unroll
            for (int ni = 0; ni < 2; ++ni) {
                const int n = wn * 32 + ni * 16 + (lane & 15);
                bfr[ni] = *reinterpret_cast<const short8*>(&Bs[n * 64 + ((t ^ (n & 7)) << 3)]);
            }
            #pragma unroll
            for (int mi = 0; mi < 4; ++mi)
                #pragma unroll
                for (int ni = 0; ni < 2; ++ni)
                    acc[mi][ni] = __builtin_amdgcn_mfma_f32_16x16x32_bf16(
                        af[mi], bfr[ni], acc[mi][ni], 0, 0, 0);
        }
        __syncthreads();
    }

    const int colb = n0 + wn * 32 + (lane & 15);
    const int rowb = m0 + wm * 64 + (lane >> 4) * 4;
    #pragma unroll
    for (int mi = 0; mi < 4; ++mi) {
        #pragma unroll
        for (int ni = 0; ni < 2; ++ni) {
            const int c = colb + ni * 16;
            #pragma unroll
            for (int j = 0; j < 4; ++j) {
                const int row = rowb + mi * 16 + j;
                const size_t off = (size_t)row * N + c;
                const float v = acc[mi][ni][j];
                if constexpr (EPI == 0) {
                    outB[off] = __float2bfloat16(v);
                } else if constexpr (EPI == 1) {
                    const float r = v + resid[off];
                    outF[off] = r;
                    outB[off] = __float2bfloat16(r);
                } else if constexpr (EPI == 2) {
                    outB[off] = __float2bfloat16(silu_f(v + bias[c]));
                } else {
                    outF[off] = v + bias[c] + resid[off];
                }
            }
        }
    }
}

// ---------------------------------------------------------------------------
// Depthwise 3x3 conv + bias + silu, x4 scan-merge, gate silu(z). Vectorized:
// thread owns 8 channels (short8 taps), 2 pixels; weights in regs, reused.
// Block: 384 thr = 48 ch-groups x 8 pixels; 2 passes -> 16 pixels/block.
// wT: fp32 [9][384] (pre-transposed conv_w).
// ---------------------------------------------------------------------------
__launch_bounds__(384)
__global__ void dwconv_gate_v2(const bf16* __restrict__ xz, const float* __restrict__ wT,
                               const float* __restrict__ conv_b, bf16* __restrict__ y)
{
    const int tid = threadIdx.x;
    const int cg  = tid % 48;          // channel group (8 ch)
    const int pl  = tid / 48;          // pixel lane 0..7
    const int c0  = cg * 8;

    float wreg[9][8];
    #pragma unroll
    for (int t = 0; t < 9; ++t) {
        const f32x4 a = *reinterpret_cast<const f32x4*>(&wT[t * CIDIM + c0]);
        const f32x4 b = *reinterpret_cast<const f32x4*>(&wT[t * CIDIM + c0 + 4]);
        wreg[t][0] = a[0]; wreg[t][1] = a[1]; wreg[t][2] = a[2]; wreg[t][3] = a[3];
        wreg[t][4] = b[0]; wreg[t][5] = b[1]; wreg[t][6] = b[2]; wreg[t][7] = b[3];
    }
    float breg[8];
    {
        const f32x4 a = *reinterpret_cast<const f32x4*>(&conv_b[c0]);
        const f32x4 b = *reinterpret_cast<const f32x4*>(&conv_b[c0 + 4]);
        breg[0] = a[0]; breg[1] = a[1]; breg[2] = a[2]; breg[3] = a[3];
        breg[4] = b[0]; breg[5] = b[1]; breg[6] = b[2]; breg[7] = b[3];
    }

    #pragma unroll
    for (int pass = 0; pass < 2; ++pass) {
        const int m   = blockIdx.x * 16 + pass * 8 + pl;
        const int b   = m >> 12;
        const int pix = m & 4095;
        const int h   = pix >> 6;
        const int w   = pix & 63;

        float acc[8];
        #pragma unroll
        for (int j = 0; j < 8; ++j) acc[j] = breg[j];

        #pragma unroll
        for (int dh = -1; dh <= 1; ++dh) {
            const int hh = h + dh;
            if (hh < 0 || hh >= HDIM) continue;
            #pragma unroll
            for (int dw = -1; dw <= 1; ++dw) {
                const int ww = w + dw;
                if (ww < 0 || ww >= WDIM) continue;
                const int mm  = (b << 12) + (hh << 6) + ww;
                const int tap = (dh + 1) * 3 + (dw + 1);
                const short8 v = *reinterpret_cast<const short8*>(&xz[(size_t)mm * 768 + c0]);
                #pragma unroll
                for (int j = 0; j < 8; ++j) acc[j] += bf2f(v[j]) * wreg[tap][j];
            }
        }

        const short8 zv = *reinterpret_cast<const short8*>(&xz[(size_t)m * 768 + CIDIM + c0]);
        bf16 tmp[8];
        #pragma unroll
        for (int j = 0; j < 8; ++j)
            tmp[j] = __float2bfloat16(4.0f * silu_f(acc[j]) * silu_f(bf2f(zv[j])));
        *reinterpret_cast<short8*>(&y[(size_t)m * CIDIM + c0]) =
            *reinterpret_cast<const short8*>(tmp);
    }
}

// ---------------------------------------------------------------------------
__launch_bounds__(256)
__global__ void cvt_to_bf16(const float* __restrict__ in, bf16* __restrict__ out, int n)
{
    const int i = (blockIdx.x * 256 + threadIdx.x) * 4;
    if (i < n) {
        const float4 v = *reinterpret_cast<const float4*>(&in[i]);
        out[i + 0] = __float2bfloat16(v.x);
        out[i + 1] = __float2bfloat16(v.y);
        out[i + 2] = __float2bfloat16(v.z);
        out[i + 3] = __float2bfloat16(v.w);
    }
}

// fp32 [R][C] -> bf16 [C][R]
__launch_bounds__(256)
__global__ void transpose_to_bf16(const float* __restrict__ in, bf16* __restrict__ out,
                                  int R, int C)
{
    const int idx = blockIdx.x * 256 + threadIdx.x;
    if (idx < R * C) {
        const int r = idx / C, c = idx % C;
        out[(size_t)c * R + r] = __float2bfloat16(in[idx]);
    }
}

// conv_w [384][9] fp32 -> wT [9][384] fp32
__launch_bounds__(256)
__global__ void transpose_convw(const float* __restrict__ in, float* __restrict__ out)
{
    const int idx = blockIdx.x * 256 + threadIdx.x;
    if (idx < CIDIM * 9) {
        const int ci = idx / 9, t = idx % 9;
        out[t * CIDIM + ci] = in[idx];
    }
}

// ---------------------------------------------------------------------------
extern "C" void kernel_launch(void* const* d_in, const int* in_sizes, int n_in,
                              void* d_out, int out_size, void* d_ws, size_t ws_size,
                              hipStream_t stream)
{
    const float* x      = (const float*)d_in[0];
    const float* Win    = (const float*)d_in[1];
    const float* conv_w = (const float*)d_in[2];
    const float* conv_b = (const float*)d_in[3];
    const float* Wout   = (const float*)d_in[4];
    const float* Wm1    = (const float*)d_in[5];
    const float* bm1    = (const float*)d_in[6];
    const float* Wm2    = (const float*)d_in[7];
    const float* bm2    = (const float*)d_in[8];
    float* out = (float*)d_out;

    char* ws = (char*)d_ws;
    size_t o = 0;
    bf16*  xb    = (bf16*)(ws + o); o += (size_t)MTOK * CDIM * 2;
    bf16*  WinT  = (bf16*)(ws + o); o += (size_t)768 * 192 * 2;
    bf16*  WoutT = (bf16*)(ws + o); o += (size_t)192 * 384 * 2;
    bf16*  Wm1T  = (bf16*)(ws + o); o += (size_t)768 * 192 * 2;
    bf16*  Wm2T  = (bf16*)(ws + o); o += (size_t)192 * 768 * 2;
    float* wTc   = (float*)(ws + o); o += (size_t)9 * CIDIM * 4;
    bf16*  ws_xz = (bf16*)(ws + o); o += (size_t)MTOK * 768 * 2;
    bf16*  ws_y  = (bf16*)(ws + o); o += (size_t)MTOK * CIDIM * 2;
    bf16*  ws_ob = (bf16*)(ws + o); o += (size_t)MTOK * CDIM * 2;
    bf16*  ws_h  = ws_xz;

    {
        const int n = MTOK * CDIM;
        cvt_to_bf16<<<dim3(n / 4 / 256), dim3(256), 0, stream>>>(x, xb, n);
        transpose_to_bf16<<<dim3((192 * 768 + 255) / 256), dim3(256), 0, stream>>>(Win,  WinT, 192, 768);
        transpose_to_bf16<<<dim3((384 * 192 + 255) / 256), dim3(256), 0, stream>>>(Wout, WoutT, 384, 192);
        transpose_to_bf16<<<dim3((192 * 768 + 255) / 256), dim3(256), 0, stream>>>(Wm1,  Wm1T, 192, 768);
        transpose_to_bf16<<<dim3((768 * 192 + 255) / 256), dim3(256), 0, stream>>>(Wm2,  Wm2T, 768, 192);
        transpose_convw<<<dim3((CIDIM * 9 + 255) / 256), dim3(256), 0, stream>>>(conv_w, wTc);
    }

    // 1) xz = x @ Win   [M,768], K=192 -> bf16
    gemm_mfma<0><<<dim3(768 / 64, MTOK / 128), dim3(256), 0, stream>>>(
        xb, WinT, nullptr, nullptr, nullptr, ws_xz, MTOK, 768, CDIM);

    // 2) y = 4*silu(dwconv(x1)+b) * silu(z) -> bf16
    dwconv_gate_v2<<<dim3(MTOK / 16), dim3(384), 0, stream>>>(ws_xz, wTc, conv_b, ws_y);

    // 3) out = x + y @ Wout   [M,192], K=384 -> fp32 + bf16
    gemm_mfma<1><<<dim3(192 / 64, MTOK / 128), dim3(256), 0, stream>>>(
        ws_y, WoutT, nullptr, x, out, ws_ob, MTOK, CDIM, CIDIM);

    // 4) h = silu(out @ Wm1 + bm1)   [M,768], K=192 -> bf16
    gemm_mfma<2><<<dim3(768 / 64, MTOK / 128), dim3(256), 0, stream>>>(
        ws_ob, Wm1T, bm1, nullptr, nullptr, ws_h, MTOK, 768, CDIM);

    // 5) final = out + h @ Wm2 + bm2   [M,192], K=768 -> fp32 (in-place)
    gemm_mfma<3><<<dim3(192 / 64, MTOK / 128), dim3(256), 0, stream>>>(
        ws_h, Wm2T, bm2, out, out, nullptr, MTOK, CDIM, 768);
}

// Round 4
// 154.867 us; speedup vs baseline: 4.5335x; 1.1315x over previous
//
#include <hip/hip_runtime.h>
#include <hip/hip_bf16.h>

// Problem constants
#define BDIM 8
#define HDIM 64
#define WDIM 64
#define CDIM 192
#define CIDIM 384
#define MTOK (BDIM * HDIM * WDIM)   // 32768 tokens

using bf16 = __hip_bfloat16;
typedef __attribute__((ext_vector_type(8))) short short8;   // 8 bf16 (4 VGPRs)
typedef __attribute__((ext_vector_type(4))) float f32x4;

__device__ __forceinline__ float silu_f(float v) { return v / (1.0f + __expf(-v)); }
__device__ __forceinline__ float bf2f(short s) {
    union { unsigned u; float f; } x; x.u = ((unsigned)(unsigned short)s) << 16; return x.f;
}

// async global->LDS, 16B per lane. LDS dest must be WAVE-UNIFORM base; HW adds lane*16.
__device__ __forceinline__ void gload_lds16(const bf16* g, bf16* l) {
    __builtin_amdgcn_global_load_lds(
        (const __attribute__((address_space(1))) void*)g,
        (__attribute__((address_space(3))) void*)l, 16, 0, 0);
}

// ---------------------------------------------------------------------------
// MFMA GEMM: C[M,N] = A[M,K] @ B[K,N], A bf16 [M,K], B given TRANSPOSED bf16 [N,K].
// BM=128, BN=64, BK=64. 256 threads = 4 waves in 2x2; wave tile 64x32 (4x2 frags).
// LDS linear [rows][64] bf16, 16B slots XOR-swizzled (both-sides: pre-swizzled
// global source + swizzled ds_read).
// EPI: 0 = store bf16; 1 = +resid -> fp32 + bf16; 2 = silu(+bias) -> bf16;
//      3 = +bias +resid -> fp32
// ---------------------------------------------------------------------------
template <int EPI>
__launch_bounds__(256, 4)
__global__ void gemm_mfma(const bf16* __restrict__ A, const bf16* __restrict__ BT,
                          const float* __restrict__ bias, const float* __restrict__ resid,
                          float* __restrict__ outF, bf16* __restrict__ outB,
                          int M, int N, int K)
{
    __shared__ bf16 As[128 * 64];
    __shared__ bf16 Bs[64 * 64];

    const int tid  = threadIdx.x;
    const int lane = tid & 63;
    const int wv   = tid >> 6;
    const int wm   = wv >> 1;
    const int wn   = wv & 1;
    const int m0   = blockIdx.y * 128;
    const int n0   = blockIdx.x * 64;

    const int srow  = lane >> 3;
    const int sslot = lane & 7;

    f32x4 acc[4][2] = {};

    for (int k0 = 0; k0 < K; k0 += 64) {
        #pragma unroll
        for (int i = 0; i < 4; ++i) {
            const int rb = wv * 32 + i * 8;
            const int r  = rb + srow;
            gload_lds16(A + (size_t)(m0 + r) * K + k0 + ((sslot ^ (r & 7)) << 3),
                        &As[rb * 64]);
        }
        #pragma unroll
        for (int i = 0; i < 2; ++i) {
            const int rb = wv * 16 + i * 8;
            const int r  = rb + srow;
            gload_lds16(BT + (size_t)(n0 + r) * K + k0 + ((sslot ^ (r & 7)) << 3),
                        &Bs[rb * 64]);
        }
        __syncthreads();

        #pragma unroll
        for (int kk = 0; kk < 2; ++kk) {
            const int t = kk * 4 + (lane >> 4);
            short8 af[4], bfr[2];
            #pragma unroll
            for (int mi = 0; mi < 4; ++mi) {
                const int m = wm * 64 + mi * 16 + (lane & 15);
                af[mi] = *reinterpret_cast<const short8*>(&As[m * 64 + ((t ^ (m & 7)) << 3)]);
            }
            #pragma unroll
            for (int ni = 0; ni < 2; ++ni) {
                const int n = wn * 32 + ni * 16 + (lane & 15);
                bfr[ni] = *reinterpret_cast<const short8*>(&Bs[n * 64 + ((t ^ (n & 7)) << 3)]);
            }
            #pragma unroll
            for (int mi = 0; mi < 4; ++mi)
                #pragma unroll
                for (int ni = 0; ni < 2; ++ni)
                    acc[mi][ni] = __builtin_amdgcn_mfma_f32_16x16x32_bf16(
                        af[mi], bfr[ni], acc[mi][ni], 0, 0, 0);
        }
        __syncthreads();
    }

    const int colb = n0 + wn * 32 + (lane & 15);
    const int rowb = m0 + wm * 64 + (lane >> 4) * 4;
    #pragma unroll
    for (int mi = 0; mi < 4; ++mi) {
        #pragma unroll
        for (int ni = 0; ni < 2; ++ni) {
            const int c = colb + ni * 16;
            #pragma unroll
            for (int j = 0; j < 4; ++j) {
                const int row = rowb + mi * 16 + j;
                const size_t off = (size_t)row * N + c;
                const float v = acc[mi][ni][j];
                if constexpr (EPI == 0) {
                    outB[off] = __float2bfloat16(v);
                } else if constexpr (EPI == 1) {
                    const float r = v + resid[off];
                    outF[off] = r;
                    outB[off] = __float2bfloat16(r);
                } else if constexpr (EPI == 2) {
                    outB[off] = __float2bfloat16(silu_f(v + bias[c]));
                } else {
                    outF[off] = v + bias[c] + resid[off];
                }
            }
        }
    }
}

// ---------------------------------------------------------------------------
// Depthwise 3x3 conv + bias + silu, x4 scan-merge, gate silu(z).  v3:
// thread = 8 channels x 4 consecutive pixels (same image row). The 4 outputs
// share tap columns: 18 independent 16B x1 loads (6 cols x 3 rows) per thread
// serve 4 pixels. Weights read per-tap from L1-hot wT [9][384].
// Block: 384 thr = 48 ch-groups x 8 pixel-groups -> 32 pixels/block. Grid 1024.
// ---------------------------------------------------------------------------
__launch_bounds__(384)
__global__ void dwconv_gate_v3(const bf16* __restrict__ xz, const float* __restrict__ wT,
                               const float* __restrict__ conv_b, bf16* __restrict__ y)
{
    const int tid = threadIdx.x;
    const int cg  = tid % 48;          // channel group (8 ch)
    const int pg  = tid / 48;          // pixel group 0..7
    const int c0  = cg * 8;
    const int p0  = blockIdx.x * 32 + pg * 4;   // 4 consecutive pixels, same row
    const int b   = p0 >> 12;
    const int pix = p0 & 4095;
    const int h   = pix >> 6;
    const int w0  = pix & 63;          // multiple of 4 -> w0..w0+3 same row

    float acc[4][8];
    {
        const f32x4 ba = *reinterpret_cast<const f32x4*>(&conv_b[c0]);
        const f32x4 bb = *reinterpret_cast<const f32x4*>(&conv_b[c0 + 4]);
        #pragma unroll
        for (int p = 0; p < 4; ++p) {
            acc[p][0] = ba[0]; acc[p][1] = ba[1]; acc[p][2] = ba[2]; acc[p][3] = ba[3];
            acc[p][4] = bb[0]; acc[p][5] = bb[1]; acc[p][6] = bb[2]; acc[p][7] = bb[3];
        }
    }

    #pragma unroll
    for (int dh = 0; dh < 3; ++dh) {
        const int hh = h + dh - 1;
        const bool rv = (hh >= 0) && (hh < HDIM);
        const size_t rowbase = (size_t)(b << 12) + ((size_t)hh << 6);

        // 6 tap columns, converted once, reused by up to 3 output pixels each
        float cv[6][8];
        #pragma unroll
        for (int dc = 0; dc < 6; ++dc) {
            const int col = w0 + dc - 1;
            short8 t = {};
            if (rv && col >= 0 && col < WDIM)
                t = *reinterpret_cast<const short8*>(&xz[(rowbase + col) * 768 + c0]);
            #pragma unroll
            for (int j = 0; j < 8; ++j) cv[dc][j] = bf2f(t[j]);
        }

        #pragma unroll
        for (int kw = 0; kw < 3; ++kw) {
            const int tap = dh * 3 + kw;
            const f32x4 wa = *reinterpret_cast<const f32x4*>(&wT[tap * CIDIM + c0]);
            const f32x4 wb = *reinterpret_cast<const f32x4*>(&wT[tap * CIDIM + c0 + 4]);
            const float wv[8] = {wa[0], wa[1], wa[2], wa[3], wb[0], wb[1], wb[2], wb[3]};
            #pragma unroll
            for (int p = 0; p < 4; ++p)
                #pragma unroll
                for (int j = 0; j < 8; ++j)
                    acc[p][j] += cv[kw + p][j] * wv[j];
        }
    }

    #pragma unroll
    for (int p = 0; p < 4; ++p) {
        const size_t m = (size_t)p0 + p;
        const short8 zv = *reinterpret_cast<const short8*>(&xz[m * 768 + CIDIM + c0]);
        bf16 tmp[8];
        #pragma unroll
        for (int j = 0; j < 8; ++j)
            tmp[j] = __float2bfloat16(4.0f * silu_f(acc[p][j]) * silu_f(bf2f(zv[j])));
        *reinterpret_cast<short8*>(&y[m * CIDIM + c0]) =
            *reinterpret_cast<const short8*>(tmp);
    }
}

// ---------------------------------------------------------------------------
__launch_bounds__(256)
__global__ void cvt_to_bf16(const float* __restrict__ in, bf16* __restrict__ out, int n)
{
    const int i = (blockIdx.x * 256 + threadIdx.x) * 4;
    if (i < n) {
        const float4 v = *reinterpret_cast<const float4*>(&in[i]);
        out[i + 0] = __float2bfloat16(v.x);
        out[i + 1] = __float2bfloat16(v.y);
        out[i + 2] = __float2bfloat16(v.z);
        out[i + 3] = __float2bfloat16(v.w);
    }
}

// ---------------------------------------------------------------------------
// All weight preprocessing in ONE launch: 4 transposed bf16 weights + conv_w
// transpose, dispatched by flat index.
// ---------------------------------------------------------------------------
#define SZ_WIN  (192 * 768)
#define SZ_WOUT (384 * 192)
#define SZ_WM1  (192 * 768)
#define SZ_WM2  (768 * 192)
#define SZ_CW   (CIDIM * 9)
#define SZ_PREP (SZ_WIN + SZ_WOUT + SZ_WM1 + SZ_WM2 + SZ_CW)

__launch_bounds__(256)
__global__ void prep_weights(const float* __restrict__ Win, const float* __restrict__ Wout,
                             const float* __restrict__ Wm1, const float* __restrict__ Wm2,
                             const float* __restrict__ convw,
                             bf16* __restrict__ WinT, bf16* __restrict__ WoutT,
                             bf16* __restrict__ Wm1T, bf16* __restrict__ Wm2T,
                             float* __restrict__ wTc)
{
    int idx = blockIdx.x * 256 + threadIdx.x;
    if (idx < SZ_WIN) {
        const int r = idx / 768, c = idx % 768;
        WinT[(size_t)c * 192 + r] = __float2bfloat16(Win[idx]);
        return;
    }
    idx -= SZ_WIN;
    if (idx < SZ_WOUT) {
        const int r = idx / 192, c = idx % 192;
        WoutT[(size_t)c * 384 + r] = __float2bfloat16(Wout[idx]);
        return;
    }
    idx -= SZ_WOUT;
    if (idx < SZ_WM1) {
        const int r = idx / 768, c = idx % 768;
        Wm1T[(size_t)c * 192 + r] = __float2bfloat16(Wm1[idx]);
        return;
    }
    idx -= SZ_WM1;
    if (idx < SZ_WM2) {
        const int r = idx / 192, c = idx % 192;
        Wm2T[(size_t)c * 768 + r] = __float2bfloat16(Wm2[idx]);
        return;
    }
    idx -= SZ_WM2;
    if (idx < SZ_CW) {
        const int ci = idx / 9, t = idx % 9;
        wTc[t * CIDIM + ci] = convw[idx];
    }
}

// ---------------------------------------------------------------------------
extern "C" void kernel_launch(void* const* d_in, const int* in_sizes, int n_in,
                              void* d_out, int out_size, void* d_ws, size_t ws_size,
                              hipStream_t stream)
{
    const float* x      = (const float*)d_in[0];
    const float* Win    = (const float*)d_in[1];
    const float* conv_w = (const float*)d_in[2];
    const float* conv_b = (const float*)d_in[3];
    const float* Wout   = (const float*)d_in[4];
    const float* Wm1    = (const float*)d_in[5];
    const float* bm1    = (const float*)d_in[6];
    const float* Wm2    = (const float*)d_in[7];
    const float* bm2    = (const float*)d_in[8];
    float* out = (float*)d_out;

    char* ws = (char*)d_ws;
    size_t o = 0;
    bf16*  xb    = (bf16*)(ws + o); o += (size_t)MTOK * CDIM * 2;
    bf16*  WinT  = (bf16*)(ws + o); o += (size_t)768 * 192 * 2;
    bf16*  WoutT = (bf16*)(ws + o); o += (size_t)192 * 384 * 2;
    bf16*  Wm1T  = (bf16*)(ws + o); o += (size_t)768 * 192 * 2;
    bf16*  Wm2T  = (bf16*)(ws + o); o += (size_t)192 * 768 * 2;
    float* wTc   = (float*)(ws + o); o += (size_t)9 * CIDIM * 4;
    bf16*  ws_xz = (bf16*)(ws + o); o += (size_t)MTOK * 768 * 2;
    bf16*  ws_y  = (bf16*)(ws + o); o += (size_t)MTOK * CIDIM * 2;
    bf16*  ws_ob = (bf16*)(ws + o); o += (size_t)MTOK * CDIM * 2;
    bf16*  ws_h  = ws_xz;

    {
        const int n = MTOK * CDIM;
        cvt_to_bf16<<<dim3(n / 4 / 256), dim3(256), 0, stream>>>(x, xb, n);
        prep_weights<<<dim3((SZ_PREP + 255) / 256), dim3(256), 0, stream>>>(
            Win, Wout, Wm1, Wm2, conv_w, WinT, WoutT, Wm1T, Wm2T, wTc);
    }

    // 1) xz = x @ Win   [M,768], K=192 -> bf16
    gemm_mfma<0><<<dim3(768 / 64, MTOK / 128), dim3(256), 0, stream>>>(
        xb, WinT, nullptr, nullptr, nullptr, ws_xz, MTOK, 768, CDIM);

    // 2) y = 4*silu(dwconv(x1)+b) * silu(z) -> bf16
    dwconv_gate_v3<<<dim3(MTOK / 32), dim3(384), 0, stream>>>(ws_xz, wTc, conv_b, ws_y);

    // 3) out = x + y @ Wout   [M,192], K=384 -> fp32 + bf16
    gemm_mfma<1><<<dim3(192 / 64, MTOK / 128), dim3(256), 0, stream>>>(
        ws_y, WoutT, nullptr, x, out, ws_ob, MTOK, CDIM, CIDIM);

    // 4) h = silu(out @ Wm1 + bm1)   [M,768], K=192 -> bf16
    gemm_mfma<2><<<dim3(768 / 64, MTOK / 128), dim3(256), 0, stream>>>(
        ws_ob, Wm1T, bm1, nullptr, nullptr, ws_h, MTOK, 768, CDIM);

    // 5) final = out + h @ Wm2 + bm2   [M,192], K=768 -> fp32 (in-place)
    gemm_mfma<3><<<dim3(192 / 64, MTOK / 128), dim3(256), 0, stream>>>(
        ws_h, Wm2T, bm2, out, out, nullptr, MTOK, CDIM, 768);
}